// Round 11
// baseline (112.149 us; speedup 1.0000x reference)
//
#include <hip/hip_runtime.h>
#include <math.h>

#define NPG    23
#define HID    48
#define HEADS  4
#define C1     192   // HEADS*HID
#define NFEAT  11
#define GG     1024  // B*T graphs
#define GRUH   64
#define FRAME  96
#define TT     16
#define BB     64

#define HSTR   196   // padded row stride for h/h1 (floats)
#define GSTR   52    // padded row stride for g
#define XSTR   12    // padded x row

// LDS layout (floats), total 9480 = 37920 B -> 4 blocks/CU
// Region0 reused: x(23*12=276) -> als2(23)+ald2(23) -> frame(96).
// H region reused: h(23*196) -> g(23*52) + h2(23*48).
#define OFF_X    0
#define OFF_ALS  280
#define OFF_ALD  372
#define OFF_H    464
#define OFF_H1   4972
#define LDSF     9480

__device__ __forceinline__ float elu_(float v) {
    return (v > 0.f) ? v : (__expf(v) - 1.f);
}

#define PHASE_FENCE() __builtin_amdgcn_sched_barrier(0)

// ---------------------------------------------------------------------------
// Kernel 1: per-graph GAT1(4h)->ELU->GAT2->ELU->pool->gi0. 256 thr, 1024
// blocks (4/CU). Round-4 tile shapes (proven ILP: VGPR~60-80, no spill) with
// two phases removed: L1 folded into B (LDS atomics), L2 folded into F's
// kc==0 epilogue. 7 phases total.
// Register rules (rounds 3-10): cap = 256/min_waves = 128 via (256,2);
// full unrolls INSIDE phases for ILP (round-10's unroll-1 at VGPR 32 was
// latency-serial and 56% slower); fences between phases stop cross-phase
// hoisting (round-7's 200-VGPR blowup).
// ---------------------------------------------------------------------------
__global__ __launch_bounds__(256, 2) void gat_fused(
    const float* __restrict__ x,      // NTOT x 11
    const float* __restrict__ W1,     // 11 x 192
    const float* __restrict__ as1,    // 192
    const float* __restrict__ ad1,    // 192
    const float* __restrict__ b1,     // 192
    const float* __restrict__ W2,     // 192 x 48
    const float* __restrict__ as2,    // 48
    const float* __restrict__ ad2,    // 48
    const float* __restrict__ b2,     // 48
    const float* __restrict__ Wih0,   // 192 x 96
    const float* __restrict__ bih0,   // 192
    float* __restrict__ gi0)          // G x 192
{
    __shared__ float S[LDSF];
    float* s_x    = S + OFF_X;               // 23 x 12 (padded)
    float* s_als  = S + OFF_ALS;             // [hh*23+n]
    float* s_ald  = S + OFF_ALD;
    float* s_h    = S + OFF_H;               // 23 x 196
    float* s_h1   = S + OFF_H1;              // 23 x 196
    float* s_g    = S + OFF_H;               // overlays h (dead after E')
    float* s_h2   = S + OFF_H + NPG * GSTR;
    float* s_als2 = S + OFF_X;               // overlays x (dead after B)
    float* s_ald2 = S + OFF_X + NPG;
    float* s_frame= S + OFF_X;               // overlays als2 (dead after H')

    const int g   = blockIdx.x;
    const int tid = threadIdx.x;

    // ---- P0: load x (padded rows); zero als/ald ----
    if (tid < NPG * NFEAT) {
        const int n = tid / NFEAT, k = tid % NFEAT;
        s_x[n * XSTR + k] = x[g * NPG * NFEAT + tid];
    }
    if (tid < 184) s_als[tid] = 0.f;   // als+ald contiguous (92+92)
    __syncthreads();
    PHASE_FENCE();

    // ---- P1: B+L1. h = x@W1, n-tile 5, W1 strip register-resident (44 regs),
    //      logit partials via LDS atomics ----
    if (tid < 240) {
        const int c4 = tid % 48, ng = tid / 48;
        const int hh = c4 / 12;
        float4 w[NFEAT];
        #pragma unroll
        for (int k = 0; k < NFEAT; k++) w[k] = *(const float4*)(W1 + k * C1 + 4 * c4);
        const float4 a_s = *(const float4*)(as1 + 4 * c4);
        const float4 a_d = *(const float4*)(ad1 + 4 * c4);
        #pragma unroll
        for (int nn = 0; nn < 5; nn++) {
            const int n = ng * 5 + nn;
            if (n < NPG) {
                float4 acc = make_float4(0.f, 0.f, 0.f, 0.f);
                #pragma unroll
                for (int k = 0; k < NFEAT; k++) {
                    const float xv = s_x[n * XSTR + k];
                    acc.x += xv * w[k].x; acc.y += xv * w[k].y;
                    acc.z += xv * w[k].z; acc.w += xv * w[k].w;
                }
                *(float4*)(s_h + n * HSTR + 4 * c4) = acc;
                atomicAdd(&s_als[hh * NPG + n],
                          acc.x * a_s.x + acc.y * a_s.y + acc.z * a_s.z + acc.w * a_s.w);
                atomicAdd(&s_ald[hh * NPG + n],
                          acc.x * a_d.x + acc.y * a_d.y + acc.z * a_d.z + acc.w * a_d.w);
            }
        }
    }
    __syncthreads();
    PHASE_FENCE();

    // ---- P2: E'. softmax1 + aggregate + b1 + ELU, j-tile 4, 8-col chunks
    //      (144 thr). Idle threads zero als2/ald2 for P3's atomics. ----
    if (tid < 144) {
        const int q = tid % 6, hh = (tid / 6) % 4, jg = tid / 24;
        const int cb = hh * HID + q * 8;
        float ald[4];
        #pragma unroll
        for (int jj = 0; jj < 4; jj++) {
            const int j = jg * 4 + jj;
            ald[jj] = s_ald[hh * NPG + ((j < NPG) ? j : NPG - 1)];
        }
        float m[4] = {-1e30f, -1e30f, -1e30f, -1e30f};
        #pragma unroll
        for (int i = 0; i < NPG; i++) {
            const float ai = s_als[hh * NPG + i];
            #pragma unroll
            for (int jj = 0; jj < 4; jj++) {
                float e = ai + ald[jj];
                e = (e > 0.f) ? e : 0.2f * e;
                m[jj] = fmaxf(m[jj], e);
            }
        }
        float ss[4] = {0.f, 0.f, 0.f, 0.f};
        float4 a0[4], a1[4];
        #pragma unroll
        for (int jj = 0; jj < 4; jj++) {
            a0[jj] = make_float4(0.f, 0.f, 0.f, 0.f);
            a1[jj] = make_float4(0.f, 0.f, 0.f, 0.f);
        }
        #pragma unroll
        for (int i = 0; i < NPG; i++) {
            const float ai = s_als[hh * NPG + i];
            const float4 hv0 = *(const float4*)(s_h + i * HSTR + cb);
            const float4 hv1 = *(const float4*)(s_h + i * HSTR + cb + 4);
            #pragma unroll
            for (int jj = 0; jj < 4; jj++) {
                float e = ai + ald[jj];
                e = (e > 0.f) ? e : 0.2f * e;
                const float p = __expf(e - m[jj]);
                ss[jj] += p;
                a0[jj].x += p * hv0.x; a0[jj].y += p * hv0.y;
                a0[jj].z += p * hv0.z; a0[jj].w += p * hv0.w;
                a1[jj].x += p * hv1.x; a1[jj].y += p * hv1.y;
                a1[jj].z += p * hv1.z; a1[jj].w += p * hv1.w;
            }
        }
        const float4 bb0 = *(const float4*)(b1 + cb);
        const float4 bb1 = *(const float4*)(b1 + cb + 4);
        #pragma unroll
        for (int jj = 0; jj < 4; jj++) {
            const int j = jg * 4 + jj;
            if (j < NPG) {
                const float inv = 1.f / (ss[jj] + 1e-16f);
                float4 v;
                v.x = elu_(a0[jj].x * inv + bb0.x);
                v.y = elu_(a0[jj].y * inv + bb0.y);
                v.z = elu_(a0[jj].z * inv + bb0.z);
                v.w = elu_(a0[jj].w * inv + bb0.w);
                *(float4*)(s_h1 + j * HSTR + cb) = v;
                v.x = elu_(a1[jj].x * inv + bb1.x);
                v.y = elu_(a1[jj].y * inv + bb1.y);
                v.z = elu_(a1[jj].z * inv + bb1.z);
                v.w = elu_(a1[jj].w * inv + bb1.w);
                *(float4*)(s_h1 + j * HSTR + cb + 4) = v;
            }
        }
    } else if (tid < 144 + 46) {
        s_als2[tid - 144] = 0.f;   // zero als2+ald2 (x region dead after B)
    }
    __syncthreads();
    PHASE_FENCE();

    // ---- P3: F+L2. g = h1 @ W2. thread=(kc 0..15, c4 0..11); W2 12xfloat4
    //      slice register-resident (W2 read ONCE/block); 16-lane shfl
    //      k-reduce; logit2 atomics folded into kc==0 epilogue ----
    if (tid < 192) {
        const int kc = tid & 15, c4 = tid >> 4;
        float4 w[12];
        #pragma unroll
        for (int r = 0; r < 12; r++)
            w[r] = *(const float4*)(W2 + (kc * 12 + r) * HID + 4 * c4);
        const float4 a_s = *(const float4*)(as2 + 4 * c4);
        const float4 a_d = *(const float4*)(ad2 + 4 * c4);
        const float* h1b = s_h1 + kc * 12;
        for (int n = 0; n < NPG; n++) {
            const float4 hv0 = *(const float4*)(h1b + n * HSTR);
            const float4 hv1 = *(const float4*)(h1b + n * HSTR + 4);
            const float4 hv2 = *(const float4*)(h1b + n * HSTR + 8);
            float4 acc;
            acc.x  = hv0.x*w[0].x;  acc.y  = hv0.x*w[0].y;  acc.z  = hv0.x*w[0].z;  acc.w  = hv0.x*w[0].w;
            acc.x += hv0.y*w[1].x;  acc.y += hv0.y*w[1].y;  acc.z += hv0.y*w[1].z;  acc.w += hv0.y*w[1].w;
            acc.x += hv0.z*w[2].x;  acc.y += hv0.z*w[2].y;  acc.z += hv0.z*w[2].z;  acc.w += hv0.z*w[2].w;
            acc.x += hv0.w*w[3].x;  acc.y += hv0.w*w[3].y;  acc.z += hv0.w*w[3].z;  acc.w += hv0.w*w[3].w;
            acc.x += hv1.x*w[4].x;  acc.y += hv1.x*w[4].y;  acc.z += hv1.x*w[4].z;  acc.w += hv1.x*w[4].w;
            acc.x += hv1.y*w[5].x;  acc.y += hv1.y*w[5].y;  acc.z += hv1.y*w[5].z;  acc.w += hv1.y*w[5].w;
            acc.x += hv1.z*w[6].x;  acc.y += hv1.z*w[6].y;  acc.z += hv1.z*w[6].z;  acc.w += hv1.z*w[6].w;
            acc.x += hv1.w*w[7].x;  acc.y += hv1.w*w[7].y;  acc.z += hv1.w*w[7].z;  acc.w += hv1.w*w[7].w;
            acc.x += hv2.x*w[8].x;  acc.y += hv2.x*w[8].y;  acc.z += hv2.x*w[8].z;  acc.w += hv2.x*w[8].w;
            acc.x += hv2.y*w[9].x;  acc.y += hv2.y*w[9].y;  acc.z += hv2.y*w[9].z;  acc.w += hv2.y*w[9].w;
            acc.x += hv2.z*w[10].x; acc.y += hv2.z*w[10].y; acc.z += hv2.z*w[10].z; acc.w += hv2.z*w[10].w;
            acc.x += hv2.w*w[11].x; acc.y += hv2.w*w[11].y; acc.z += hv2.w*w[11].z; acc.w += hv2.w*w[11].w;
            #pragma unroll
            for (int d = 1; d < 16; d <<= 1) {
                acc.x += __shfl_xor(acc.x, d, 64);
                acc.y += __shfl_xor(acc.y, d, 64);
                acc.z += __shfl_xor(acc.z, d, 64);
                acc.w += __shfl_xor(acc.w, d, 64);
            }
            if (kc == 0) {
                *(float4*)(s_g + n * GSTR + 4 * c4) = acc;
                atomicAdd(&s_als2[n],
                          acc.x * a_s.x + acc.y * a_s.y + acc.z * a_s.z + acc.w * a_s.w);
                atomicAdd(&s_ald2[n],
                          acc.x * a_d.x + acc.y * a_d.y + acc.z * a_d.z + acc.w * a_d.w);
            }
        }
    }
    __syncthreads();
    PHASE_FENCE();

    // ---- P4: H'. softmax2 + aggregate + b2 + ELU, j-tile 2 (48 thr) ----
    if (tid < 48) {
        const int q = tid & 3, jp = tid >> 2;
        const int j0 = 2 * jp, j1 = 2 * jp + 1;
        const bool has1 = (j1 < NPG);
        const int cb = q * 12;
        const float ald0 = s_ald2[j0];
        const float ald1 = has1 ? s_ald2[j1] : 0.f;
        float m0 = -1e30f, m1 = -1e30f;
        #pragma unroll
        for (int i = 0; i < NPG; i++) {
            const float ai = s_als2[i];
            float e0 = ai + ald0; e0 = (e0 > 0.f) ? e0 : 0.2f * e0;
            float e1 = ai + ald1; e1 = (e1 > 0.f) ? e1 : 0.2f * e1;
            m0 = fmaxf(m0, e0); m1 = fmaxf(m1, e1);
        }
        float4 acc0[3], acc1[3];
        #pragma unroll
        for (int c = 0; c < 3; c++) {
            acc0[c] = make_float4(0.f, 0.f, 0.f, 0.f);
            acc1[c] = make_float4(0.f, 0.f, 0.f, 0.f);
        }
        float ss0 = 0.f, ss1 = 0.f;
        #pragma unroll
        for (int i = 0; i < NPG; i++) {
            const float ai = s_als2[i];
            float e0 = ai + ald0; e0 = (e0 > 0.f) ? e0 : 0.2f * e0;
            float e1 = ai + ald1; e1 = (e1 > 0.f) ? e1 : 0.2f * e1;
            const float p0 = __expf(e0 - m0); ss0 += p0;
            const float p1 = __expf(e1 - m1); ss1 += p1;
            const float* gp = s_g + i * GSTR + cb;
            #pragma unroll
            for (int c = 0; c < 3; c++) {
                const float4 gv = *(const float4*)(gp + 4 * c);
                acc0[c].x += p0 * gv.x; acc0[c].y += p0 * gv.y;
                acc0[c].z += p0 * gv.z; acc0[c].w += p0 * gv.w;
                acc1[c].x += p1 * gv.x; acc1[c].y += p1 * gv.y;
                acc1[c].z += p1 * gv.z; acc1[c].w += p1 * gv.w;
            }
        }
        const float inv0 = 1.f / (ss0 + 1e-16f);
        const float inv1 = 1.f / (ss1 + 1e-16f);
        #pragma unroll
        for (int c = 0; c < 3; c++) {
            const float4 bb = *(const float4*)(b2 + cb + 4 * c);
            float4 v;
            v.x = elu_(acc0[c].x * inv0 + bb.x);
            v.y = elu_(acc0[c].y * inv0 + bb.y);
            v.z = elu_(acc0[c].z * inv0 + bb.z);
            v.w = elu_(acc0[c].w * inv0 + bb.w);
            *(float4*)(s_h2 + j0 * HID + cb + 4 * c) = v;
            if (has1) {
                v.x = elu_(acc1[c].x * inv1 + bb.x);
                v.y = elu_(acc1[c].y * inv1 + bb.y);
                v.z = elu_(acc1[c].z * inv1 + bb.z);
                v.w = elu_(acc1[c].w * inv1 + bb.w);
                *(float4*)(s_h2 + j1 * HID + cb + 4 * c) = v;
            }
        }
    }
    __syncthreads();
    PHASE_FENCE();

    // ---- P5: pool -> s_frame (96 thr: 48 sum + 48 max) ----
    if (tid < 96) {
        const int col = tid % 48, half = tid / 48;
        if (half == 0) {
            float sm = 0.f;
            #pragma unroll
            for (int j = 0; j < NPG; j++) sm += s_h2[j * HID + col];
            s_frame[col] = sm * (1.0f / NPG);
        } else {
            float mx = -1e30f;
            #pragma unroll
            for (int j = 0; j < NPG; j++) mx = fmaxf(mx, s_h2[j * HID + col]);
            s_frame[HID + col] = mx;
        }
    }
    __syncthreads();
    PHASE_FENCE();

    // ---- P6: gi0 row = frame . Wih0^T + bih0 (192 thr, dot-96 each) ----
    if (tid < C1) {
        float s = bih0[tid];
        const float4* wr = (const float4*)(Wih0 + tid * FRAME);
        const float4* fr = (const float4*)s_frame;
        #pragma unroll 4
        for (int k4 = 0; k4 < FRAME / 4; k4++) {
            const float4 w = wr[k4];
            const float4 f = fr[k4];
            s += w.x * f.x + w.y * f.y + w.z * f.z + w.w * f.w;
        }
        gi0[g * C1 + tid] = s;
    }
}

// ---------------------------------------------------------------------------
// Kernel 2: 2-layer GRU (T=16) + MLP head. 384 thr/block, 64 blocks.
// gi0 precomputed by gat. k-split-2 pipeline (row=tid>>1, kh=tid&1, pair
// shfl; layer-1 one step behind layer-0; 2 barriers/step). [round-10 proven]
// ---------------------------------------------------------------------------
__global__ __launch_bounds__(384) void gru_head(
    const float* __restrict__ gi0g,   // (B*T) x 192 (bih0 already added)
    const float* __restrict__ Whh0,   // 192 x 64
    const float* __restrict__ bhh0,
    const float* __restrict__ Wih1,   // 192 x 64
    const float* __restrict__ bih1,
    const float* __restrict__ Whh1,   // 192 x 64
    const float* __restrict__ bhh1,
    const float* __restrict__ Wh1,    // 64 x 32
    const float* __restrict__ bh1,
    const float* __restrict__ Wh2,    // 32 x 1
    const float* __restrict__ bh2,
    float* __restrict__ out)          // 64
{
    __shared__ float s_gi0[TT * C1];
    __shared__ float s_h0[GRUH], s_h1[GRUH];
    __shared__ float s_gh0[C1], s_gi1[C1], s_gh1[C1];
    __shared__ float s_t1[32];

    const int b = blockIdx.x, tid = threadIdx.x;

    {   // load gi0 (16 x 192 = 768 float4), 2 per thread, coalesced
        const float4* src = (const float4*)(gi0g + b * TT * C1);
        float4* dst = (float4*)s_gi0;
        dst[tid]       = src[tid];
        dst[tid + 384] = src[tid + 384];
    }
    if (tid < GRUH) { s_h0[tid] = 0.f; s_h1[tid] = 0.f; }

    const int row = tid >> 1, kh = tid & 1;
    float w0[32], w1[32], w2[32];
    {
        const float4* p0 = (const float4*)(Whh0 + row * 64 + kh * 32);
        const float4* p1 = (const float4*)(Wih1 + row * 64 + kh * 32);
        const float4* p2 = (const float4*)(Whh1 + row * 64 + kh * 32);
        #pragma unroll
        for (int k4 = 0; k4 < 8; k4++) {
            const float4 v0 = p0[k4];
            w0[4*k4] = v0.x; w0[4*k4+1] = v0.y; w0[4*k4+2] = v0.z; w0[4*k4+3] = v0.w;
            const float4 v1 = p1[k4];
            w1[4*k4] = v1.x; w1[4*k4+1] = v1.y; w1[4*k4+2] = v1.z; w1[4*k4+3] = v1.w;
            const float4 v2 = p2[k4];
            w2[4*k4] = v2.x; w2[4*k4+1] = v2.y; w2[4*k4+2] = v2.z; w2[4*k4+3] = v2.w;
        }
    }
    const float bh0r = kh ? 0.f : bhh0[row];
    const float bi1r = kh ? 0.f : bih1[row];
    const float bh1r = kh ? 0.f : bhh1[row];
    __syncthreads();   // covers gi0 writes

    for (int it = 0; it <= TT; it++) {
        // P1: partial dots over this thread's k-half, pair-combine via shfl
        {
            float s0 = bh0r, s1 = bi1r, s2 = bh1r;
            const float4* h0v = (const float4*)(s_h0 + kh * 32);
            const float4* h1v = (const float4*)(s_h1 + kh * 32);
            #pragma unroll
            for (int k4 = 0; k4 < 8; k4++) {
                const float4 a = h0v[k4];
                const float4 c = h1v[k4];
                s0 += w0[4*k4]*a.x + w0[4*k4+1]*a.y + w0[4*k4+2]*a.z + w0[4*k4+3]*a.w;
                s1 += w1[4*k4]*a.x + w1[4*k4+1]*a.y + w1[4*k4+2]*a.z + w1[4*k4+3]*a.w;
                s2 += w2[4*k4]*c.x + w2[4*k4+1]*c.y + w2[4*k4+2]*c.z + w2[4*k4+3]*c.w;
            }
            s0 += __shfl_xor(s0, 1, 64);
            s1 += __shfl_xor(s1, 1, 64);
            s2 += __shfl_xor(s2, 1, 64);
            if (kh == 0) { s_gh0[row] = s0; s_gi1[row] = s1; s_gh1[row] = s2; }
        }
        __syncthreads();
        // P2: update h0[it] (lanes 0..63) and h1[it-1] (lanes 64..127)
        if (tid < GRUH) {
            if (it < TT) {
                const float ir = s_gi0[it*C1 + tid];
                const float iz = s_gi0[it*C1 + 64 + tid];
                const float in_ = s_gi0[it*C1 + 128 + tid];
                const float hr = s_gh0[tid], hz = s_gh0[64 + tid], hn = s_gh0[128 + tid];
                const float r = 1.f / (1.f + __expf(-(ir + hr)));
                const float z = 1.f / (1.f + __expf(-(iz + hz)));
                const float nx = in_ + r * hn;
                const float e2 = __expf(2.f * nx);
                const float n = (e2 - 1.f) / (e2 + 1.f);
                s_h0[tid] = (1.f - z) * n + z * s_h0[tid];
            }
        } else if (tid < 2 * GRUH) {
            if (it >= 1) {
                const int c = tid - GRUH;
                const float ir = s_gi1[c], iz = s_gi1[64 + c], in_ = s_gi1[128 + c];
                const float hr = s_gh1[c], hz = s_gh1[64 + c], hn = s_gh1[128 + c];
                const float r = 1.f / (1.f + __expf(-(ir + hr)));
                const float z = 1.f / (1.f + __expf(-(iz + hz)));
                const float nx = in_ + r * hn;
                const float e2 = __expf(2.f * nx);
                const float n = (e2 - 1.f) / (e2 + 1.f);
                s_h1[c] = (1.f - z) * n + z * s_h1[c];
            }
        }
        __syncthreads();
    }

    // ---- head: relu(h1[15] @ Wh1 + bh1) @ Wh2 + bh2 ----
    if (tid < 32) {
        float s = bh1[tid];
        #pragma unroll
        for (int k = 0; k < GRUH; k++) s += s_h1[k] * Wh1[k * 32 + tid];
        s_t1[tid] = fmaxf(s, 0.f);
    }
    __syncthreads();
    if (tid == 0) {
        float s = bh2[0];
        #pragma unroll
        for (int k = 0; k < 32; k++) s += s_t1[k] * Wh2[k];
        out[b] = s;
    }
}

extern "C" void kernel_launch(void* const* d_in, const int* in_sizes, int n_in,
                              void* d_out, int out_size, void* d_ws, size_t ws_size,
                              hipStream_t stream) {
    const float* x    = (const float*)d_in[0];
    // d_in[1] = edge_index, d_in[2] = batch : fixed dense structure -> unused
    const float* W1   = (const float*)d_in[3];
    const float* as1  = (const float*)d_in[4];
    const float* ad1  = (const float*)d_in[5];
    const float* b1   = (const float*)d_in[6];
    const float* W2   = (const float*)d_in[7];
    const float* as2  = (const float*)d_in[8];
    const float* ad2  = (const float*)d_in[9];
    const float* b2   = (const float*)d_in[10];
    const float* Wih0 = (const float*)d_in[11];
    const float* Whh0 = (const float*)d_in[12];
    const float* bih0 = (const float*)d_in[13];
    const float* bhh0 = (const float*)d_in[14];
    const float* Wih1 = (const float*)d_in[15];
    const float* Whh1 = (const float*)d_in[16];
    const float* bih1 = (const float*)d_in[17];
    const float* bhh1 = (const float*)d_in[18];
    const float* Wh1  = (const float*)d_in[19];
    const float* bh1  = (const float*)d_in[20];
    const float* Wh2  = (const float*)d_in[21];
    const float* bh2  = (const float*)d_in[22];

    float* out  = (float*)d_out;
    float* gi0  = (float*)d_ws;   // G x 192 fp32 = 786 KB

    hipLaunchKernelGGL(gat_fused, dim3(GG), dim3(256), 0, stream,
                       x, W1, as1, ad1, b1, W2, as2, ad2, b2, Wih0, bih0, gi0);
    hipLaunchKernelGGL(gru_head, dim3(BB), dim3(384), 0, stream,
                       gi0, Whh0, bhh0, Wih1, bih1, Whh1, bhh1,
                       Wh1, bh1, Wh2, bh2, out);
}